// Round 3
// baseline (94.870 us; speedup 1.0000x reference)
//
#include <hip/hip_runtime.h>

// Problem constants (fixed by reference)
#define BATCH 2
#define NPTS  2048
#define CIN   64
#define COUT  128
#define GD    14                 // padded grid dim: vox in [0,11] -> +1 shift, halo -> [0,13]
#define GD2   (GD*GD)            // 196
#define NCELL (GD*GD*GD)         // 2744
#define M     (BATCH*NPTS)       // 4096
#define VOXF  (BATCH*NCELL*CIN)  // 351232 floats
#define WTEL  (27*COUT*CIN)      // 221184 bf16 elements (transposed weight)

typedef __bf16 bf16x8 __attribute__((ext_vector_type(8)));
typedef float  f32x4  __attribute__((ext_vector_type(4)));
typedef unsigned short us8 __attribute__((ext_vector_type(8)));

__device__ __forceinline__ unsigned short f2bf(float f) {
    unsigned u = __builtin_bit_cast(unsigned, f);
    return (unsigned short)((u + 0x7FFFu + ((u >> 16) & 1u)) >> 16);  // RNE
}

// Kernel 1: blocks 0..26 transpose weight[off] (64k x 128n fp32) -> bf16 wT[off][n][k]
//           blocks 27..42 compute abase[g] = (b*NCELL + cell)*CIN for each point.
__global__ __launch_bounds__(256) void k_init(const float* __restrict__ points,
                                              const float* __restrict__ weight,
                                              int* __restrict__ abase,
                                              unsigned short* __restrict__ wT) {
    const int t = threadIdx.x;
    if (blockIdx.x < 27) {
        const int off = blockIdx.x;
        __shared__ unsigned short lds[128*65 + 64];
        const float* wsrc = weight + off*8192;
        #pragma unroll
        for (int i = 0; i < 32; ++i) {           // load coalesced over n, cvt, store LDS
            const int s = t + i*256;             // s < 8192
            const int k = s >> 7, n = s & 127;
            lds[n*65 + k] = f2bf(wsrc[k*128 + n]);
        }
        __syncthreads();
        unsigned short* wdst = wT + off*8192;
        #pragma unroll
        for (int i = 0; i < 32; ++i) {           // write coalesced over k
            const int s = t + i*256;
            const int n = s >> 6, k = s & 63;
            wdst[n*64 + k] = lds[n*65 + k];
        }
    } else {
        const int g = (blockIdx.x - 27)*256 + t; // g < M (16 blocks * 256 = 4096)
        const int vx = (int)points[g*3 + 0];
        const int vy = (int)points[g*3 + 1];
        const int vz = (int)points[g*3 + 2];
        const int cell = (vx + 1)*GD2 + (vy + 1)*GD + (vz + 1);
        abase[g] = ((g >> 11)*NCELL + cell)*CIN;
    }
}

// Kernel 2: scatter-add features into the fp32 voxel grid.
__global__ __launch_bounds__(256) void k_scatter(const float* __restrict__ feat,
                                                 const int* __restrict__ abase,
                                                 float* __restrict__ voxgrid) {
    const int idx = blockIdx.x * 256 + threadIdx.x;   // [0, M*CIN)
    const int g   = idx >> 6;
    const int cin = idx & 63;
    atomicAdd(&voxgrid[abase[g] + cin], feat[idx]);
}

// Kernel 3: convert fp32 voxgrid -> bf16 voxbf (whole grid incl. zero halo).
__global__ __launch_bounds__(256) void k_pack(const float* __restrict__ voxgrid,
                                              unsigned short* __restrict__ voxbf) {
    const int idx = blockIdx.x * 256 + threadIdx.x;   // [0, VOXF/8)
    if (idx >= VOXF/8) return;
    const float4 v0 = ((const float4*)voxgrid)[idx*2 + 0];
    const float4 v1 = ((const float4*)voxgrid)[idx*2 + 1];
    us8 p;
    p[0] = f2bf(v0.x); p[1] = f2bf(v0.y); p[2] = f2bf(v0.z); p[3] = f2bf(v0.w);
    p[4] = f2bf(v1.x); p[5] = f2bf(v1.y); p[6] = f2bf(v1.z); p[7] = f2bf(v1.w);
    *(us8*)(voxbf + idx*8) = p;
}

// Kernel 4: MFMA gather-GEMM. No LDS, no barriers: each wave owns a 16x16 C-tile,
// loads A-fragments straight from bf16 voxgrid (one 16B load per mfma operand).
// Block = 4 independent waves (4 n-tiles); grid (M/16, 2) -> 2048 waves = 8/CU.
__global__ __launch_bounds__(256) void k_gemm(const unsigned short* __restrict__ voxbf,
                                              const int* __restrict__ abase,
                                              const unsigned short* __restrict__ wT,
                                              const float* __restrict__ bias,
                                              float* __restrict__ out) {
    static constexpr int DELTA[27] = {
        -211,-210,-209,-197,-196,-195,-183,-182,-181,
         -15, -14, -13,  -1,   0,   1,  13,  14,  15,
         181, 182, 183, 195, 196, 197, 209, 210, 211 };

    const int t   = threadIdx.x;
    const int l   = t & 63;
    const int w   = t >> 6;
    const int q   = l >> 4;            // lane quad
    const int col = l & 15;            // A-row (m) and B-col (n) lane index
    const int g0  = blockIdx.x * 16;
    const int n0  = (blockIdx.y * 4 + w) * 16;

    const int rowoff = abase[g0 + col];                        // element offset of this m-row
    const unsigned short* arow = voxbf + rowoff + q*8;         // + delta*CIN (+32 for k-hi)
    const unsigned short* wtp  = wT + (size_t)(n0 + col)*CIN + q*8;  // + off*8192 (+32)

    f32x4 acc = {0.f, 0.f, 0.f, 0.f};

    us8 A0[3], A1[3], B0[3], B1[3];
    #pragma unroll
    for (int p = 0; p < 3; ++p) {                              // prolog: fill 3-deep pipeline
        const int d = DELTA[p]*CIN;
        A0[p] = *(const us8*)(arow + d);
        A1[p] = *(const us8*)(arow + d + 32);
        B0[p] = *(const us8*)(wtp + p*8192);
        B1[p] = *(const us8*)(wtp + p*8192 + 32);
    }

    #pragma unroll
    for (int oo = 0; oo < 27; ++oo) {
        const int s = oo % 3;
        const us8 a0 = A0[s], a1 = A1[s], b0 = B0[s], b1 = B1[s];
        if (oo + 3 < 27) {
            const int d = DELTA[oo+3]*CIN;
            A0[s] = *(const us8*)(arow + d);
            A1[s] = *(const us8*)(arow + d + 32);
            B0[s] = *(const us8*)(wtp + (oo+3)*8192);
            B1[s] = *(const us8*)(wtp + (oo+3)*8192 + 32);
        }
        acc = __builtin_amdgcn_mfma_f32_16x16x32_bf16(
                  __builtin_bit_cast(bf16x8, a0), __builtin_bit_cast(bf16x8, b0), acc, 0, 0, 0);
        acc = __builtin_amdgcn_mfma_f32_16x16x32_bf16(
                  __builtin_bit_cast(bf16x8, a1), __builtin_bit_cast(bf16x8, b1), acc, 0, 0, 0);
    }

    // epilogue: C/D layout col = lane&15, row = q*4 + r
    const float bs = bias[n0 + col];
    #pragma unroll
    for (int r = 0; r < 4; ++r) {
        out[(size_t)(g0 + q*4 + r)*COUT + n0 + col] = acc[r] + bs;
    }
}

extern "C" void kernel_launch(void* const* d_in, const int* in_sizes, int n_in,
                              void* d_out, int out_size, void* d_ws, size_t ws_size,
                              hipStream_t stream) {
    (void)in_sizes; (void)n_in; (void)out_size; (void)ws_size;
    const float* points   = (const float*)d_in[0];  // (2,2048,3)
    const float* features = (const float*)d_in[1];  // (2,2048,64)
    const float* weight   = (const float*)d_in[2];  // (3,3,3,64,128)
    const float* bias     = (const float*)d_in[3];  // (128,)
    float* out = (float*)d_out;                     // (2,2048,128)

    char* ws = (char*)d_ws;
    float*          voxgrid = (float*)ws;                            // VOXF fp32   (1404928 B)
    int*            abase   = (int*)(ws + 1404928);                  // M ints      (16384 B)
    unsigned short* wTp     = (unsigned short*)(ws + 1404928 + 16384);        // WTEL bf16 (442368 B)
    unsigned short* voxbf   = (unsigned short*)(ws + 1404928 + 16384 + 442368); // VOXF bf16

    hipMemsetAsync(voxgrid, 0, (size_t)VOXF*4, stream);
    k_init<<<43, 256, 0, stream>>>(points, weight, abase, wTp);
    k_scatter<<<(M*CIN)/256, 256, 0, stream>>>(features, abase, voxgrid);
    k_pack<<<(VOXF/8 + 255)/256, 256, 0, stream>>>(voxgrid, voxbf);
    dim3 grid(M/16, 2, 1);
    k_gemm<<<grid, 256, 0, stream>>>(voxbf, abase, wTp, bias, out);
}